// Round 3
// baseline (313.536 us; speedup 1.0000x reference)
//
#include <hip/hip_runtime.h>
#include <hip/hip_bf16.h>

typedef __bf16 bf16_t;
typedef __bf16 bf16x4 __attribute__((ext_vector_type(4)));
typedef __bf16 bf16x8 __attribute__((ext_vector_type(8)));
typedef float  f32x4  __attribute__((ext_vector_type(4)));

// ---------------------------------------------------------------- helpers
__device__ __forceinline__ void gload_lds16(const void* g, void* l)
{
    __builtin_amdgcn_global_load_lds((__attribute__((address_space(1))) void*)g,
                                     (__attribute__((address_space(3))) void*)l,
                                     16, 0, 0);
}

// ---------------------------------------------------------------- fused fp32 -> bf16 casts (x1|x2 -> xcat, W1, W2)
__global__ __launch_bounds__(256) void cast_all(const float* __restrict__ x1, const float* __restrict__ x2,
                                                const float* __restrict__ W1, const float* __restrict__ W2,
                                                bf16_t* __restrict__ xcatb, bf16_t* __restrict__ W1b,
                                                bf16_t* __restrict__ W2b)
{
    const size_t i  = ((size_t)blockIdx.x * 256 + threadIdx.x) * 4;
    const size_t M4 = 1ull << 22;              // 4M elements per region
    const size_t r  = i >> 22;
    const size_t off = i & (M4 - 1);
    const float* src; bf16_t* dst;
    if (r == 0)      { src = x1; dst = xcatb; }
    else if (r == 1) { src = x2; dst = xcatb + M4; }
    else if (r == 2) { src = W1; dst = W1b; }
    else             { src = W2; dst = W2b; }
    f32x4 v = *(const f32x4*)(src + off);
    bf16x4 o;
    o[0] = (bf16_t)v[0]; o[1] = (bf16_t)v[1]; o[2] = (bf16_t)v[2]; o[3] = (bf16_t)v[3];
    *(bf16x4*)(dst + off) = o;
}

// ---------------------------------------------------------------- NT GEMM, m97 structure, BK=128
// C[m,n] = sum_k A[m,k]*B[n,k] + bias[n]; 128x128 tile, 4 waves (2x2), 16x16x32 MFMA.
// Single-buffered stage -> sync -> compute -> sync (implicit wave-level overlap does the pipelining).
// mode 0: bias only. mode 1: + per-block column sum/sumsq partials (BN stats).
// mode 2: + per-block row argmax partials (packed uint64 keys, diag excluded).
__global__ __launch_bounds__(256) void gemm_bt(
    const bf16_t* __restrict__ A, const bf16_t* __restrict__ B,
    const float* __restrict__ bias, float* __restrict__ C,
    int N, int K, int rows_per_batch, long long b_batch_stride,
    int mode, float* __restrict__ ps, float* __restrict__ ps2,
    unsigned long long* __restrict__ pkey)
{
    __shared__ bf16_t lsA[128 * 128];
    __shared__ bf16_t lsB[128 * 128];
    const int tid  = threadIdx.x;
    const int lane = tid & 63;
    const int wave = tid >> 6;
    const int wm   = (wave >> 1) * 64;
    const int wn   = (wave & 1) * 64;
    const int m0   = blockIdx.y * 128;
    const int n0   = blockIdx.x * 128;
    const bf16_t* Bb = B + (long long)(m0 / rows_per_batch) * b_batch_stride;

    f32x4 acc[4][4] = {};

    const int srow = tid >> 4;          // staging: 256 threads cover 16 rows x 16 chunks of 16B
    const int scol = (tid & 15) * 8;    // element offset within BK=128

    for (int kt = 0; kt < K; kt += 128) {
#pragma unroll
        for (int i = 0; i < 8; ++i) {
            const int r = i * 16 + srow;
            // LDS dest = wave-uniform base + lane*16B (linear, required for global_load_lds)
            gload_lds16(A  + (size_t)(m0 + r) * K + kt + scol, lsA + r * 128 + scol);
            gload_lds16(Bb + (size_t)(n0 + r) * K + kt + scol, lsB + r * 128 + scol);
        }
        __syncthreads();  // compiler drains vmcnt before barrier
#pragma unroll
        for (int ks = 0; ks < 4; ++ks) {
            const int kk = ks * 32 + (lane >> 4) * 8;
            bf16x8 af[4], bfr[4];
#pragma unroll
            for (int f = 0; f < 4; ++f) {
                af[f]  = *(const bf16x8*)&lsA[(wm + f * 16 + (lane & 15)) * 128 + kk];
                bfr[f] = *(const bf16x8*)&lsB[(wn + f * 16 + (lane & 15)) * 128 + kk];
            }
#pragma unroll
            for (int fm = 0; fm < 4; ++fm)
#pragma unroll
                for (int fn = 0; fn < 4; ++fn)
                    acc[fm][fn] = __builtin_amdgcn_mfma_f32_16x16x32_bf16(af[fm], bfr[fn], acc[fm][fn], 0, 0, 0);
        }
        __syncthreads();
    }

    // ---- C write (+bias). C/D layout: col = lane&15, row = (lane>>4)*4 + reg  [m89-verified]
#pragma unroll
    for (int fm = 0; fm < 4; ++fm) {
        const int rb = m0 + wm + fm * 16 + ((lane >> 4) << 2);
#pragma unroll
        for (int fn = 0; fn < 4; ++fn) {
            const int colg = n0 + wn + fn * 16 + (lane & 15);
            const float bv = bias ? bias[colg] : 0.0f;
#pragma unroll
            for (int r = 0; r < 4; ++r)
                C[(size_t)(rb + r) * N + colg] = acc[fm][fn][r] + bv;
        }
    }

    if (mode == 1) {
        // per-block column sum / sumsq over the 128 rows (2 commutative LDS atomics per col -> deterministic)
        __shared__ float cs[128], cq[128];
        if (tid < 128) { cs[tid] = 0.f; cq[tid] = 0.f; }
        __syncthreads();
#pragma unroll
        for (int fn = 0; fn < 4; ++fn) {
            const int coll = wn + fn * 16 + (lane & 15);
            const float bv = bias[n0 + coll];
            float s = 0.f, q = 0.f;
#pragma unroll
            for (int fm = 0; fm < 4; ++fm)
#pragma unroll
                for (int r = 0; r < 4; ++r) {
                    const float v = acc[fm][fn][r] + bv;
                    s += v; q += v * v;
                }
            s += __shfl_xor(s, 16); q += __shfl_xor(q, 16);
            s += __shfl_xor(s, 32); q += __shfl_xor(q, 32);
            if (lane < 16) { atomicAdd(&cs[coll], s); atomicAdd(&cq[coll], q); }
        }
        __syncthreads();
        if (tid < 128) {
            ps [(size_t)blockIdx.y * 2048 + n0 + tid] = cs[tid];
            ps2[(size_t)blockIdx.y * 2048 + n0 + tid] = cq[tid];
        }
    } else if (mode == 2) {
        // per-block row argmax partial; key = ordered(val)<<32 | ~col (max => max val, tie => min col)
        __shared__ unsigned long long kv[128];
        if (tid < 128) kv[tid] = 0ull;
        __syncthreads();
#pragma unroll
        for (int fm = 0; fm < 4; ++fm)
#pragma unroll
            for (int r = 0; r < 4; ++r) {
                const int rowl = wm + fm * 16 + ((lane >> 4) << 2) + r;
                const int self = (m0 + rowl) & 2047;
                float best = -1.0e38f; int bi = 0x7fffffff;
#pragma unroll
                for (int fn = 0; fn < 4; ++fn) {
                    const int cg = n0 + wn + fn * 16 + (lane & 15);
                    const float v = acc[fm][fn][r];
                    if (cg != self && v > best) { best = v; bi = cg; }
                }
#pragma unroll
                for (int st = 1; st <= 8; st <<= 1) {
                    const float ov = __shfl_xor(best, st);
                    const int   oi = __shfl_xor(bi, st);
                    if (ov > best || (ov == best && oi < bi)) { best = ov; bi = oi; }
                }
                if ((lane & 15) == 0) {
                    unsigned u = __float_as_uint(best);
                    u = (u & 0x80000000u) ? ~u : (u | 0x80000000u);
                    const unsigned long long key = ((unsigned long long)u << 32) | (unsigned)(~bi);
                    atomicMax(&kv[rowl], key);   // commutative/idempotent -> deterministic
                }
            }
        __syncthreads();
        if (tid < 128) pkey[(size_t)blockIdx.x * 4096 + m0 + tid] = kv[tid];
    }
}

// ---------------------------------------------------------------- BN finalize from 16 per-mblock partials
__global__ __launch_bounds__(256) void bn_final2(const float* __restrict__ ps, const float* __restrict__ ps2,
                                                 float* __restrict__ mu, float* __restrict__ rinv)
{
    const int c = blockIdx.x * 256 + threadIdx.x;  // 0..4095
    const int b = c >> 11, col = c & 2047;
    float s = 0.f, s2 = 0.f;
    for (int i = 0; i < 16; ++i) {
        s  += ps [(size_t)(b * 16 + i) * 2048 + col];
        s2 += ps2[(size_t)(b * 16 + i) * 2048 + col];
    }
    const float m = s * (1.0f / 2048.0f);
    const float v = s2 * (1.0f / 2048.0f) - m * m;   // biased var
    mu[c]   = m;
    rinv[c] = rsqrtf(v + 1e-5f);
}

// ---------------------------------------------------------------- BN apply + ReLU + cast to bf16
__global__ __launch_bounds__(256) void bn_apply(const float* __restrict__ h, const float* __restrict__ mu,
                                                const float* __restrict__ rinv, const float* __restrict__ gamma,
                                                const float* __restrict__ beta, bf16_t* __restrict__ out)
{
    const size_t base = ((size_t)blockIdx.x * 256 + threadIdx.x) * 4;
    const int row = (int)(base >> 11);
    const int col = (int)(base & 2047);
    const int br  = row >> 11;
    f32x4 v = *(const f32x4*)(h + base);
    bf16x4 o;
#pragma unroll
    for (int j = 0; j < 4; ++j) {
        const int c = col + j;
        float t = (v[j] - mu[br * 2048 + c]) * rinv[br * 2048 + c] * gamma[c] + beta[c];
        o[j] = (bf16_t)fmaxf(t, 0.0f);
    }
    *(bf16x4*)(out + base) = o;
}

// ---------------------------------------------------------------- row L2-normalize + cast to bf16
__global__ __launch_bounds__(256) void rownorm(const float* __restrict__ o, bf16_t* __restrict__ feat)
{
    const int row = blockIdx.x;
    const int t = threadIdx.x;
    const float* p = o + (size_t)row * 2048;
    f32x4 v0 = *(const f32x4*)(p + t * 4);
    f32x4 v1 = *(const f32x4*)(p + 1024 + t * 4);
    float ss = v0[0]*v0[0] + v0[1]*v0[1] + v0[2]*v0[2] + v0[3]*v0[3]
             + v1[0]*v1[0] + v1[1]*v1[1] + v1[2]*v1[2] + v1[3]*v1[3];
    __shared__ float S[256];
    S[t] = ss;
    __syncthreads();
    for (int off = 128; off; off >>= 1) { if (t < off) S[t] += S[t + off]; __syncthreads(); }
    const float rn = 1.0f / fmaxf(sqrtf(S[0]), 1e-12f);
    bf16x4 o0, o1;
#pragma unroll
    for (int j = 0; j < 4; ++j) { o0[j] = (bf16_t)(v0[j] * rn); o1[j] = (bf16_t)(v1[j] * rn); }
    *(bf16x4*)(feat + (size_t)row * 2048 + t * 4) = o0;
    *(bf16x4*)(feat + (size_t)row * 2048 + 1024 + t * 4) = o1;
}

// ---------------------------------------------------------------- argmax combine over 16 n-block partials
__global__ __launch_bounds__(256) void argmax_combine(const unsigned long long* __restrict__ pkey,
                                                      int* __restrict__ y)
{
    const int row = blockIdx.x * 256 + threadIdx.x;  // 0..4095
    unsigned long long k = 0ull;
    for (int nb = 0; nb < 16; ++nb) {
        const unsigned long long v = pkey[(size_t)nb * 4096 + row];
        k = (v > k) ? v : k;
    }
    y[row] = (int)~((unsigned)(k & 0xFFFFFFFFull));
}

// ---------------------------------------------------------------- connected components via min-propagation (1 block/branch)
__global__ __launch_bounds__(1024) void cc_labels(const int* __restrict__ yg, int* __restrict__ labg)
{
    __shared__ int A_[2048];
    __shared__ int Bn[2048];
    __shared__ int Y_[2048];
    const int br = blockIdx.x;
    const int t = threadIdx.x;
    for (int i = t; i < 2048; i += 1024) { Y_[i] = yg[br * 2048 + i]; A_[i] = i; }
    __syncthreads();
    for (int it = 0; it < 32; ++it) {
        for (int i = t; i < 2048; i += 1024) Bn[i] = min(A_[i], A_[Y_[i]]);   // ln = min(l, l[y])
        __syncthreads();
        for (int i = t; i < 2048; i += 1024) atomicMin(&Bn[Y_[i]], A_[i]);    // ln = ln.at[y].min(l)
        __syncthreads();
        for (int i = t; i < 2048; i += 1024) { int b = Bn[i]; A_[i] = min(b, Bn[b]); } // pointer jump
        __syncthreads();
    }
    for (int i = t; i < 2048; i += 1024) labg[br * 2048 + i] = A_[i];
}

// ---------------------------------------------------------------- per-row contrastive term: lse - possum/poscnt
__global__ __launch_bounds__(256) void loss_rows(const float* __restrict__ sim, const int* __restrict__ labels,
                                                 float* __restrict__ terms)
{
    const int row = blockIdx.x;
    const int br  = row >> 11;
    const int* lab = labels + ((1 - br) << 11);  // mask from the OTHER branch's labels
    const int self = row & 2047;
    const int li = lab[self];
    const int t = threadIdx.x;
    const f32x4* p = (const f32x4*)(sim + (size_t)row * 2048);
    f32x4 a = p[t * 2], b = p[t * 2 + 1];
    float se = 0.f, psum = 0.f; int pc = 0;
#pragma unroll
    for (int j = 0; j < 8; ++j) {
        const int c = t * 8 + j;
        const float v = (j < 4) ? a[j] : b[j - 4];
        if (c == self) continue;
        const float lg = v * 10.0f;   // 1/T
        se += expf(lg);
        if (lab[c] == li) { psum += lg; pc++; }
    }
    __shared__ float SE[256], PS[256]; __shared__ int PC[256];
    SE[t] = se; PS[t] = psum; PC[t] = pc;
    __syncthreads();
    for (int off = 128; off; off >>= 1) {
        if (t < off) { SE[t] += SE[t + off]; PS[t] += PS[t + off]; PC[t] += PC[t + off]; }
        __syncthreads();
    }
    if (t == 0) terms[row] = logf(SE[0]) - PS[0] / (float)PC[0];
}

// ---------------------------------------------------------------- final deterministic reduce
__global__ __launch_bounds__(1024) void final_reduce(const float* __restrict__ terms, float* __restrict__ out)
{
    const int t = threadIdx.x;
    float s = terms[t] + terms[t + 1024] + terms[t + 2048] + terms[t + 3072];
    __shared__ float S[1024];
    S[t] = s;
    __syncthreads();
    for (int off = 512; off; off >>= 1) { if (t < off) S[t] += S[t + off]; __syncthreads(); }
    if (t == 0) out[0] = S[0] * (1.0f / 4096.0f);   // (L1+L2)/2, each mean over 2048 rows
}

// ---------------------------------------------------------------- launch
extern "C" void kernel_launch(void* const* d_in, const int* in_sizes, int n_in,
                              void* d_out, int out_size, void* d_ws, size_t ws_size,
                              hipStream_t stream)
{
    const float* x1    = (const float*)d_in[0];
    const float* x2    = (const float*)d_in[1];
    const float* W1    = (const float*)d_in[2];
    const float* b1    = (const float*)d_in[3];
    const float* gamma = (const float*)d_in[4];
    const float* beta  = (const float*)d_in[5];
    const float* W2    = (const float*)d_in[6];
    const float* b2    = (const float*)d_in[7];

    char* ws = (char*)d_ws;
    const size_t MB = 1024ull * 1024ull;
    const size_t NN = 2048ull * 2048ull;
    // Region plan (reuse as regions go dead):
    //  [0,8M)   W1b      (dead after GEMM1)
    //  [8,16M)  W2b      (dead after GEMM2)
    //  [16,32M) xcatb -> hnb (xcatb dead after GEMM1; hnb dead after GEMM2)
    //  [32,64M) h -> o   (dead after rownorm)
    //  [0,32M)  sim      (written by GEMM3 after W1b/W2b/hnb dead)
    //  [64,80M) featb
    //  [80M..)  partials + small buffers
    bf16_t* W1b    = (bf16_t*)(ws + 0);
    bf16_t* W2b    = (bf16_t*)(ws + 8 * MB);
    bf16_t* xcatb  = (bf16_t*)(ws + 16 * MB);
    bf16_t* hnb    = (bf16_t*)(ws + 16 * MB);
    float*  hbuf   = (float*)(ws + 32 * MB);
    float*  sim    = (float*)(ws + 0);
    bf16_t* featb  = (bf16_t*)(ws + 64 * MB);
    float*  psA    = (float*)(ws + 80 * MB);              // [32][2048] col sums
    float*  psB    = psA + 32 * 2048;                      // [32][2048] col sumsq
    float*  mu     = psB + 32 * 2048;                      // [2][2048]
    float*  rinv   = mu + 4096;
    unsigned long long* pkey = (unsigned long long*)(rinv + 4096);  // [16][4096]
    int*    yidx   = (int*)(pkey + 16 * 4096);
    int*    labels = yidx + 4096;
    float*  terms  = (float*)(labels + 4096);

    // fused casts
    cast_all<<<16384, 256, 0, stream>>>(x1, x2, W1, W2, xcatb, W1b, W2b);

    // h = xcat @ W1^T + b1 (M=4096,N=2048,K=2048), fused BN-stat partials
    gemm_bt<<<dim3(16, 32), 256, 0, stream>>>(xcatb, W1b, b1, hbuf, 2048, 2048, 1 << 30, 0,
                                              1, psA, psB, nullptr);
    bn_final2<<<16, 256, 0, stream>>>(psA, psB, mu, rinv);
    bn_apply<<<8192, 256, 0, stream>>>(hbuf, mu, rinv, gamma, beta, hnb);

    // o = hn @ W2^T + b2
    gemm_bt<<<dim3(16, 32), 256, 0, stream>>>(hnb, W2b, b2, hbuf, 2048, 2048, 1 << 30, 0,
                                              0, nullptr, nullptr, nullptr);

    // feat = normalize(o) -> bf16
    rownorm<<<4096, 256, 0, stream>>>(hbuf, featb);

    // sim = [feat1@feat1^T ; feat2@feat2^T], fused row-argmax partials
    gemm_bt<<<dim3(16, 32), 256, 0, stream>>>(featb, featb, nullptr, sim, 2048, 2048, 2048, (long long)NN,
                                              2, nullptr, nullptr, pkey);
    argmax_combine<<<16, 256, 0, stream>>>(pkey, yidx);

    // CC -> loss
    cc_labels<<<2, 1024, 0, stream>>>(yidx, labels);
    loss_rows<<<4096, 256, 0, stream>>>(sim, labels, terms);
    final_reduce<<<1, 1024, 0, stream>>>(terms, (float*)d_out);
}

// Round 4
// 271.607 us; speedup vs baseline: 1.1544x; 1.1544x over previous
//
#include <hip/hip_runtime.h>
#include <hip/hip_bf16.h>

typedef __bf16 bf16_t;
typedef __bf16 bf16x4 __attribute__((ext_vector_type(4)));
typedef __bf16 bf16x8 __attribute__((ext_vector_type(8)));
typedef float  f32x4  __attribute__((ext_vector_type(4)));

// ---------------------------------------------------------------- helpers
__device__ __forceinline__ void gload_lds16(const void* g, void* l)
{
    __builtin_amdgcn_global_load_lds((__attribute__((address_space(1))) void*)g,
                                     (__attribute__((address_space(3))) void*)l,
                                     16, 0, 0);
}

// ---------------------------------------------------------------- fused fp32 -> bf16 casts (x1|x2 -> xcat, W1, W2)
__global__ __launch_bounds__(256) void cast_all(const float* __restrict__ x1, const float* __restrict__ x2,
                                                const float* __restrict__ W1, const float* __restrict__ W2,
                                                bf16_t* __restrict__ xcatb, bf16_t* __restrict__ W1b,
                                                bf16_t* __restrict__ W2b)
{
    const size_t i  = ((size_t)blockIdx.x * 256 + threadIdx.x) * 4;
    const size_t M4 = 1ull << 22;              // 4M elements per region
    const size_t r  = i >> 22;
    const size_t off = i & (M4 - 1);
    const float* src; bf16_t* dst;
    if (r == 0)      { src = x1; dst = xcatb; }
    else if (r == 1) { src = x2; dst = xcatb + M4; }
    else if (r == 2) { src = W1; dst = W1b; }
    else             { src = W2; dst = W2b; }
    f32x4 v = *(const f32x4*)(src + off);
    bf16x4 o;
    o[0] = (bf16_t)v[0]; o[1] = (bf16_t)v[1]; o[2] = (bf16_t)v[2]; o[3] = (bf16_t)v[3];
    *(bf16x4*)(dst + off) = o;
}

// ---------------------------------------------------------------- NT GEMM, m97 inner loop, 128x64 tile, BK=64
// C[m,n] = sum_k A[m,k]*B[n,k] + bias[n]; 4 waves (2 m-halves x 2 n-halves), wave = 64x32, 16x16x32 MFMA.
// Single-buffered stage -> sync -> compute -> sync (implicit wave-level overlap does the pipelining).
// mode 0: bias only. mode 1: + per-mblock column sum/sumsq partials (BN stats), atomic-free.
// mode 2: + per-nblock row argmax partials (packed uint64 keys, diag excluded), atomic-free.
__global__ __launch_bounds__(256) void gemm_bt(
    const bf16_t* __restrict__ A, const bf16_t* __restrict__ B,
    const float* __restrict__ bias, float* __restrict__ C,
    int N, int K, int rows_per_batch, long long b_batch_stride,
    int mode, float* __restrict__ ps, float* __restrict__ ps2,
    unsigned long long* __restrict__ pkey)
{
    __shared__ bf16_t lsA[128 * 64];
    __shared__ bf16_t lsB[64 * 64];
    __shared__ float  csq[4][64];                 // mode1: [mhalf][s|q][64 cols] (2x2 packed)
    __shared__ unsigned long long kvh[2][128];    // mode2: [nhalf][row]
    const int tid  = threadIdx.x;
    const int lane = tid & 63;
    const int wave = tid >> 6;
    const int wm   = (wave >> 1) * 64;            // m-half
    const int wn   = (wave & 1) * 32;             // n-half
    const int m0   = blockIdx.y * 128;
    const int n0   = blockIdx.x * 64;
    const bf16_t* Bb = B + (long long)(m0 / rows_per_batch) * b_batch_stride;

    f32x4 acc[4][2] = {};

    const int srow = tid >> 3;        // 256 threads cover 32 rows x 8 chunks of 16B
    const int scol = (tid & 7) * 8;

    for (int kt = 0; kt < K; kt += 64) {
#pragma unroll
        for (int i = 0; i < 4; ++i) {
            const int r = i * 32 + srow;
            gload_lds16(A + (size_t)(m0 + r) * K + kt + scol, lsA + r * 64 + scol);
        }
#pragma unroll
        for (int i = 0; i < 2; ++i) {
            const int r = i * 32 + srow;
            gload_lds16(Bb + (size_t)(n0 + r) * K + kt + scol, lsB + r * 64 + scol);
        }
        __syncthreads();  // compiler drains vmcnt before barrier
#pragma unroll
        for (int ks = 0; ks < 2; ++ks) {
            const int kk = ks * 32 + (lane >> 4) * 8;
            bf16x8 af[4], bfr[2];
#pragma unroll
            for (int f = 0; f < 4; ++f)
                af[f]  = *(const bf16x8*)&lsA[(wm + f * 16 + (lane & 15)) * 64 + kk];
#pragma unroll
            for (int g = 0; g < 2; ++g)
                bfr[g] = *(const bf16x8*)&lsB[(wn + g * 16 + (lane & 15)) * 64 + kk];
#pragma unroll
            for (int fm = 0; fm < 4; ++fm)
#pragma unroll
                for (int fn = 0; fn < 2; ++fn)
                    acc[fm][fn] = __builtin_amdgcn_mfma_f32_16x16x32_bf16(af[fm], bfr[fn], acc[fm][fn], 0, 0, 0);
        }
        __syncthreads();
    }

    // ---- C write (+bias). C/D layout: col = lane&15, row = (lane>>4)*4 + reg  [m89-verified]
#pragma unroll
    for (int fm = 0; fm < 4; ++fm) {
        const int rb = m0 + wm + fm * 16 + ((lane >> 4) << 2);
#pragma unroll
        for (int fn = 0; fn < 2; ++fn) {
            const int colg = n0 + wn + fn * 16 + (lane & 15);
            const float bv = bias ? bias[colg] : 0.0f;
#pragma unroll
            for (int r = 0; r < 4; ++r)
                C[(size_t)(rb + r) * N + colg] = acc[fm][fn][r] + bv;
        }
    }

    if (mode == 1) {
        // column sum/sumsq over this block's 128 rows; unique-writer LDS slots -> deterministic, no atomics
#pragma unroll
        for (int fn = 0; fn < 2; ++fn) {
            const int coll = wn + fn * 16 + (lane & 15);
            const float bv = bias[n0 + coll];
            float s = 0.f, q = 0.f;
#pragma unroll
            for (int fm = 0; fm < 4; ++fm)
#pragma unroll
                for (int r = 0; r < 4; ++r) {
                    const float v = acc[fm][fn][r] + bv;
                    s += v; q += v * v;
                }
            s += __shfl_xor(s, 16); q += __shfl_xor(q, 16);
            s += __shfl_xor(s, 32); q += __shfl_xor(q, 32);
            if (lane < 16) {                       // lanes 0..15 hold cols coll for this wave
                csq[(wave >> 1) * 2 + 0][coll] = s;  // [mhalf*2+0] = sum
                csq[(wave >> 1) * 2 + 1][coll] = q;  // [mhalf*2+1] = sumsq
            }
        }
        __syncthreads();
        if (tid < 64) {
            ps [(size_t)blockIdx.y * 2048 + n0 + tid] = csq[0][tid] + csq[2][tid];
            ps2[(size_t)blockIdx.y * 2048 + n0 + tid] = csq[1][tid] + csq[3][tid];
        }
    } else if (mode == 2) {
        // row argmax over this block's 64 cols; key = ordered(val)<<32 | ~col; unique-writer slots
#pragma unroll
        for (int fm = 0; fm < 4; ++fm)
#pragma unroll
            for (int r = 0; r < 4; ++r) {
                const int rowl = wm + fm * 16 + ((lane >> 4) << 2) + r;
                const int self = (m0 + rowl) & 2047;
                float best = -1.0e38f; int bi = 0x7fffffff;
#pragma unroll
                for (int fn = 0; fn < 2; ++fn) {
                    const int cg = n0 + wn + fn * 16 + (lane & 15);
                    const float v = acc[fm][fn][r];
                    if (cg != self && v > best) { best = v; bi = cg; }
                }
#pragma unroll
                for (int st = 1; st <= 8; st <<= 1) {
                    const float ov = __shfl_xor(best, st);
                    const int   oi = __shfl_xor(bi, st);
                    if (ov > best || (ov == best && oi < bi)) { best = ov; bi = oi; }
                }
                if ((lane & 15) == 0) {            // lanes 0,16,32,48 -> 4 distinct rows
                    unsigned u = __float_as_uint(best);
                    u = (u & 0x80000000u) ? ~u : (u | 0x80000000u);
                    kvh[wave & 1][rowl] = ((unsigned long long)u << 32) | (unsigned)(~bi);
                }
            }
        __syncthreads();
        if (tid < 128) {
            const unsigned long long a = kvh[0][tid], b = kvh[1][tid];
            pkey[(size_t)blockIdx.x * 4096 + m0 + tid] = a > b ? a : b;
        }
    }
}

// ---------------------------------------------------------------- BN finalize from 16 per-mblock partials
__global__ __launch_bounds__(256) void bn_final2(const float* __restrict__ ps, const float* __restrict__ ps2,
                                                 float* __restrict__ mu, float* __restrict__ rinv)
{
    const int c = blockIdx.x * 256 + threadIdx.x;  // 0..4095
    const int b = c >> 11, col = c & 2047;
    float s = 0.f, s2 = 0.f;
    for (int i = 0; i < 16; ++i) {
        s  += ps [(size_t)(b * 16 + i) * 2048 + col];
        s2 += ps2[(size_t)(b * 16 + i) * 2048 + col];
    }
    const float m = s * (1.0f / 2048.0f);
    const float v = s2 * (1.0f / 2048.0f) - m * m;   // biased var
    mu[c]   = m;
    rinv[c] = rsqrtf(v + 1e-5f);
}

// ---------------------------------------------------------------- BN apply + ReLU + cast to bf16
__global__ __launch_bounds__(256) void bn_apply(const float* __restrict__ h, const float* __restrict__ mu,
                                                const float* __restrict__ rinv, const float* __restrict__ gamma,
                                                const float* __restrict__ beta, bf16_t* __restrict__ out)
{
    const size_t base = ((size_t)blockIdx.x * 256 + threadIdx.x) * 4;
    const int row = (int)(base >> 11);
    const int col = (int)(base & 2047);
    const int br  = row >> 11;
    f32x4 v = *(const f32x4*)(h + base);
    bf16x4 o;
#pragma unroll
    for (int j = 0; j < 4; ++j) {
        const int c = col + j;
        float t = (v[j] - mu[br * 2048 + c]) * rinv[br * 2048 + c] * gamma[c] + beta[c];
        o[j] = (bf16_t)fmaxf(t, 0.0f);
    }
    *(bf16x4*)(out + base) = o;
}

// ---------------------------------------------------------------- row L2-normalize + cast to bf16
__global__ __launch_bounds__(256) void rownorm(const float* __restrict__ o, bf16_t* __restrict__ feat)
{
    const int row = blockIdx.x;
    const int t = threadIdx.x;
    const float* p = o + (size_t)row * 2048;
    f32x4 v0 = *(const f32x4*)(p + t * 4);
    f32x4 v1 = *(const f32x4*)(p + 1024 + t * 4);
    float ss = v0[0]*v0[0] + v0[1]*v0[1] + v0[2]*v0[2] + v0[3]*v0[3]
             + v1[0]*v1[0] + v1[1]*v1[1] + v1[2]*v1[2] + v1[3]*v1[3];
    __shared__ float S[256];
    S[t] = ss;
    __syncthreads();
    for (int off = 128; off; off >>= 1) { if (t < off) S[t] += S[t + off]; __syncthreads(); }
    const float rn = 1.0f / fmaxf(sqrtf(S[0]), 1e-12f);
    bf16x4 o0, o1;
#pragma unroll
    for (int j = 0; j < 4; ++j) { o0[j] = (bf16_t)(v0[j] * rn); o1[j] = (bf16_t)(v1[j] * rn); }
    *(bf16x4*)(feat + (size_t)row * 2048 + t * 4) = o0;
    *(bf16x4*)(feat + (size_t)row * 2048 + 1024 + t * 4) = o1;
}

// ---------------------------------------------------------------- CC (argmax-combine folded in), 1 block/branch
__global__ __launch_bounds__(1024) void cc_labels(const unsigned long long* __restrict__ pkey,
                                                  int* __restrict__ labg)
{
    __shared__ int A_[2048];
    __shared__ int Bn[2048];
    __shared__ int Y_[2048];
    const int br = blockIdx.x;
    const int t = threadIdx.x;
    // fold: per-row max over the 32 n-block partials -> kNN neighbor
    for (int i = t; i < 2048; i += 1024) {
        const int row = br * 2048 + i;
        unsigned long long k = 0ull;
        for (int nb = 0; nb < 32; ++nb) {
            const unsigned long long v = pkey[(size_t)nb * 4096 + row];
            k = (v > k) ? v : k;
        }
        Y_[i] = (int)~((unsigned)(k & 0xFFFFFFFFull));
        A_[i] = i;
    }
    __syncthreads();
    for (int it = 0; it < 32; ++it) {
        for (int i = t; i < 2048; i += 1024) Bn[i] = min(A_[i], A_[Y_[i]]);   // ln = min(l, l[y])
        __syncthreads();
        for (int i = t; i < 2048; i += 1024) atomicMin(&Bn[Y_[i]], A_[i]);    // ln = ln.at[y].min(l)
        __syncthreads();
        for (int i = t; i < 2048; i += 1024) { int b = Bn[i]; A_[i] = min(b, Bn[b]); } // pointer jump
        __syncthreads();
    }
    for (int i = t; i < 2048; i += 1024) labg[br * 2048 + i] = A_[i];
}

// ---------------------------------------------------------------- per-row contrastive term: lse - possum/poscnt
__global__ __launch_bounds__(256) void loss_rows(const float* __restrict__ sim, const int* __restrict__ labels,
                                                 float* __restrict__ terms)
{
    const int row = blockIdx.x;
    const int br  = row >> 11;
    const int* lab = labels + ((1 - br) << 11);  // mask from the OTHER branch's labels
    const int self = row & 2047;
    const int li = lab[self];
    const int t = threadIdx.x;
    const f32x4* p = (const f32x4*)(sim + (size_t)row * 2048);
    f32x4 a = p[t * 2], b = p[t * 2 + 1];
    float se = 0.f, psum = 0.f; int pc = 0;
#pragma unroll
    for (int j = 0; j < 8; ++j) {
        const int c = t * 8 + j;
        const float v = (j < 4) ? a[j] : b[j - 4];
        if (c == self) continue;
        const float lg = v * 10.0f;   // 1/T
        se += expf(lg);
        if (lab[c] == li) { psum += lg; pc++; }
    }
    __shared__ float SE[256], PS[256]; __shared__ int PC[256];
    SE[t] = se; PS[t] = psum; PC[t] = pc;
    __syncthreads();
    for (int off = 128; off; off >>= 1) {
        if (t < off) { SE[t] += SE[t + off]; PS[t] += PS[t + off]; PC[t] += PC[t + off]; }
        __syncthreads();
    }
    if (t == 0) terms[row] = logf(SE[0]) - PS[0] / (float)PC[0];
}

// ---------------------------------------------------------------- final deterministic reduce
__global__ __launch_bounds__(1024) void final_reduce(const float* __restrict__ terms, float* __restrict__ out)
{
    const int t = threadIdx.x;
    float s = terms[t] + terms[t + 1024] + terms[t + 2048] + terms[t + 3072];
    __shared__ float S[1024];
    S[t] = s;
    __syncthreads();
    for (int off = 512; off; off >>= 1) { if (t < off) S[t] += S[t + off]; __syncthreads(); }
    if (t == 0) out[0] = S[0] * (1.0f / 4096.0f);   // (L1+L2)/2, each mean over 2048 rows
}

// ---------------------------------------------------------------- launch
extern "C" void kernel_launch(void* const* d_in, const int* in_sizes, int n_in,
                              void* d_out, int out_size, void* d_ws, size_t ws_size,
                              hipStream_t stream)
{
    const float* x1    = (const float*)d_in[0];
    const float* x2    = (const float*)d_in[1];
    const float* W1    = (const float*)d_in[2];
    const float* b1    = (const float*)d_in[3];
    const float* gamma = (const float*)d_in[4];
    const float* beta  = (const float*)d_in[5];
    const float* W2    = (const float*)d_in[6];
    const float* b2    = (const float*)d_in[7];

    char* ws = (char*)d_ws;
    const size_t MB = 1024ull * 1024ull;
    const size_t NN = 2048ull * 2048ull;
    // Region plan (reuse as regions go dead):
    //  [0,8M)   W1b      (dead after GEMM1)
    //  [8,16M)  W2b      (dead after GEMM2)
    //  [16,32M) xcatb -> hnb (xcatb dead after GEMM1; hnb dead after GEMM2)
    //  [32,64M) h -> o   (dead after rownorm)
    //  [0,32M)  sim      (written by GEMM3 after W1b/W2b/hnb dead)
    //  [64,80M) featb
    //  [80M..)  partials + small buffers
    bf16_t* W1b    = (bf16_t*)(ws + 0);
    bf16_t* W2b    = (bf16_t*)(ws + 8 * MB);
    bf16_t* xcatb  = (bf16_t*)(ws + 16 * MB);
    bf16_t* hnb    = (bf16_t*)(ws + 16 * MB);
    float*  hbuf   = (float*)(ws + 32 * MB);
    float*  sim    = (float*)(ws + 0);
    bf16_t* featb  = (bf16_t*)(ws + 64 * MB);
    float*  psA    = (float*)(ws + 80 * MB);              // [32][2048] col sums
    float*  psB    = psA + 32 * 2048;                      // [32][2048] col sumsq
    float*  mu     = psB + 32 * 2048;                      // [2][2048]
    float*  rinv   = mu + 4096;
    unsigned long long* pkey = (unsigned long long*)(rinv + 4096);  // [32][4096]
    int*    labels = (int*)(pkey + 32 * 4096);
    float*  terms  = (float*)(labels + 4096);

    // fused casts
    cast_all<<<16384, 256, 0, stream>>>(x1, x2, W1, W2, xcatb, W1b, W2b);

    // h = xcat @ W1^T + b1 (M=4096,N=2048,K=2048), fused BN-stat partials
    gemm_bt<<<dim3(32, 32), 256, 0, stream>>>(xcatb, W1b, b1, hbuf, 2048, 2048, 1 << 30, 0,
                                              1, psA, psB, nullptr);
    bn_final2<<<16, 256, 0, stream>>>(psA, psB, mu, rinv);
    bn_apply<<<8192, 256, 0, stream>>>(hbuf, mu, rinv, gamma, beta, hnb);

    // o = hn @ W2^T + b2
    gemm_bt<<<dim3(32, 32), 256, 0, stream>>>(hnb, W2b, b2, hbuf, 2048, 2048, 1 << 30, 0,
                                              0, nullptr, nullptr, nullptr);

    // feat = normalize(o) -> bf16
    rownorm<<<4096, 256, 0, stream>>>(hbuf, featb);

    // sim = [feat1@feat1^T ; feat2@feat2^T], fused row-argmax partials
    gemm_bt<<<dim3(32, 32), 256, 0, stream>>>(featb, featb, nullptr, sim, 2048, 2048, 2048, (long long)NN,
                                              2, nullptr, nullptr, pkey);

    // CC (argmax folded) -> loss
    cc_labels<<<2, 1024, 0, stream>>>(pkey, labels);
    loss_rows<<<4096, 256, 0, stream>>>(sim, labels, terms);
    final_reduce<<<1, 1024, 0, stream>>>(terms, (float*)d_out);
}

// Round 5
// 244.589 us; speedup vs baseline: 1.2819x; 1.1105x over previous
//
#include <hip/hip_runtime.h>
#include <hip/hip_bf16.h>

typedef __bf16 bf16_t;
typedef __bf16 bf16x4 __attribute__((ext_vector_type(4)));
typedef __bf16 bf16x8 __attribute__((ext_vector_type(8)));
typedef float  f32x4  __attribute__((ext_vector_type(4)));

// ---------------------------------------------------------------- helpers
__device__ __forceinline__ void gload_lds16(const void* g, void* l)
{
    __builtin_amdgcn_global_load_lds((__attribute__((address_space(1))) void*)g,
                                     (__attribute__((address_space(3))) void*)l,
                                     16, 0, 0);
}

// ---------------------------------------------------------------- fused fp32 -> bf16 casts (x1|x2 -> xcat, W1, W2)
__global__ __launch_bounds__(256) void cast_all(const float* __restrict__ x1, const float* __restrict__ x2,
                                                const float* __restrict__ W1, const float* __restrict__ W2,
                                                bf16_t* __restrict__ xcatb, bf16_t* __restrict__ W1b,
                                                bf16_t* __restrict__ W2b)
{
    const size_t i  = ((size_t)blockIdx.x * 256 + threadIdx.x) * 4;
    const size_t M4 = 1ull << 22;              // 4M elements per region
    const size_t r  = i >> 22;
    const size_t off = i & (M4 - 1);
    const float* src; bf16_t* dst;
    if (r == 0)      { src = x1; dst = xcatb; }
    else if (r == 1) { src = x2; dst = xcatb + M4; }
    else if (r == 2) { src = W1; dst = W1b; }
    else             { src = W2; dst = W2b; }
    f32x4 v = *(const f32x4*)(src + off);
    bf16x4 o;
    o[0] = (bf16_t)v[0]; o[1] = (bf16_t)v[1]; o[2] = (bf16_t)v[2]; o[3] = (bf16_t)v[3];
    *(bf16x4*)(dst + off) = o;
}

// ---------------------------------------------------------------- NT GEMM, exact R1/m97 structure: 128x128 tile, BK=64
// C[m,n] = sum_k A[m,k]*B[n,k] + bias[n]; 4 waves (2x2), each wave 64x64 via 4x4 frags of 16x16x32 MFMA.
// Single-buffered stage -> sync -> compute -> sync (implicit wave-level overlap does the pipelining).
// mode 0: bias only. mode 1: + per-mblock column sum/sumsq partials (BN stats), atomic-free unique-writer.
// mode 2: + per-nblock row argmax partials (packed uint64 keys, diag excluded), atomic-free unique-writer.
__global__ __launch_bounds__(256) void gemm_bt(
    const bf16_t* __restrict__ A, const bf16_t* __restrict__ B,
    const float* __restrict__ bias, float* __restrict__ C,
    int N, int K, int rows_per_batch, long long b_batch_stride,
    int mode, float* __restrict__ ps, float* __restrict__ ps2,
    unsigned long long* __restrict__ pkey)
{
    __shared__ bf16_t lsA[128 * 64];
    __shared__ bf16_t lsB[128 * 64];
    __shared__ float  cs2[4][64];                 // mode1: per-wave col sums   (unique writer)
    __shared__ float  cq2[4][64];                 // mode1: per-wave col sumsqs (unique writer)
    __shared__ unsigned long long kv2[4][64];     // mode2: per-wave row keys   (unique writer)
    const int tid  = threadIdx.x;
    const int lane = tid & 63;
    const int wave = tid >> 6;
    const int wm   = (wave >> 1) * 64;
    const int wn   = (wave & 1) * 64;
    const int m0   = blockIdx.y * 128;
    const int n0   = blockIdx.x * 128;
    const bf16_t* Bb = B + (long long)(m0 / rows_per_batch) * b_batch_stride;

    f32x4 acc[4][4] = {};

    const int srow = tid >> 3;        // staging: 256 threads cover 32 rows x 8 chunks of 16B
    const int scol = (tid & 7) * 8;   // element offset within BK
    for (int kt = 0; kt < K; kt += 64) {
#pragma unroll
        for (int i = 0; i < 4; ++i) {
            const int r = i * 32 + srow;
            // LDS byte offset = i*4096 + tid*16 -> wave-uniform base + lane*16 (linear dest, required)
            gload_lds16(A  + (size_t)(m0 + r) * K + kt + scol, lsA + r * 64 + scol);
            gload_lds16(Bb + (size_t)(n0 + r) * K + kt + scol, lsB + r * 64 + scol);
        }
        __syncthreads();  // compiler drains vmcnt before barrier
#pragma unroll
        for (int ks = 0; ks < 2; ++ks) {
            const int kk = ks * 32 + (lane >> 4) * 8;
            bf16x8 af[4], bfr[4];
#pragma unroll
            for (int f = 0; f < 4; ++f) {
                af[f]  = *(const bf16x8*)&lsA[(wm + f * 16 + (lane & 15)) * 64 + kk];
                bfr[f] = *(const bf16x8*)&lsB[(wn + f * 16 + (lane & 15)) * 64 + kk];
            }
#pragma unroll
            for (int fm = 0; fm < 4; ++fm)
#pragma unroll
                for (int fn = 0; fn < 4; ++fn)
                    acc[fm][fn] = __builtin_amdgcn_mfma_f32_16x16x32_bf16(af[fm], bfr[fn], acc[fm][fn], 0, 0, 0);
        }
        __syncthreads();
    }

    // ---- C write (+bias). C/D layout: col = lane&15, row = (lane>>4)*4 + reg  [m89-verified]
#pragma unroll
    for (int fm = 0; fm < 4; ++fm) {
        const int rb = m0 + wm + fm * 16 + ((lane >> 4) << 2);
#pragma unroll
        for (int fn = 0; fn < 4; ++fn) {
            const int colg = n0 + wn + fn * 16 + (lane & 15);
            const float bv = bias ? bias[colg] : 0.0f;
#pragma unroll
            for (int r = 0; r < 4; ++r)
                C[(size_t)(rb + r) * N + colg] = acc[fm][fn][r] + bv;
        }
    }

    if (mode == 1) {
        // column sum/sumsq over this block's 128 rows. Wave w covers cols [wn,wn+64) x rows [wm,wm+64);
        // waves {0,2} share cols 0..63 (different m-half), {1,3} share cols 64..127. Unique-writer slots.
#pragma unroll
        for (int fn = 0; fn < 4; ++fn) {
            const int cl = fn * 16 + (lane & 15);      // 0..63 within wave's col range
            const float bv = bias[n0 + wn + cl];
            float s = 0.f, q = 0.f;
#pragma unroll
            for (int fm = 0; fm < 4; ++fm)
#pragma unroll
                for (int r = 0; r < 4; ++r) {
                    const float v = acc[fm][fn][r] + bv;
                    s += v; q += v * v;
                }
            s += __shfl_xor(s, 16); q += __shfl_xor(q, 16);
            s += __shfl_xor(s, 32); q += __shfl_xor(q, 32);
            if (lane < 16) { cs2[wave][cl] = s; cq2[wave][cl] = q; }
        }
        __syncthreads();
        if (tid < 128) {
            const int wlo = (tid < 64) ? 0 : 1;        // waves covering this col: {0,2} or {1,3}
            const int cl  = tid & 63;
            ps [(size_t)blockIdx.y * 2048 + n0 + tid] = cs2[wlo][cl] + cs2[wlo + 2][cl];
            ps2[(size_t)blockIdx.y * 2048 + n0 + tid] = cq2[wlo][cl] + cq2[wlo + 2][cl];
        }
    } else if (mode == 2) {
        // row argmax over this block's 128 cols; key = ordered(val)<<32 | ~col (max => max val, tie => min col).
        // Wave w covers rows [wm,wm+64); waves {0,1} share rows 0..63, {2,3} rows 64..127. Unique-writer slots.
#pragma unroll
        for (int fm = 0; fm < 4; ++fm)
#pragma unroll
            for (int r = 0; r < 4; ++r) {
                const int rl   = fm * 16 + ((lane >> 4) << 2) + r;  // 0..63 within wave's row range
                const int self = (m0 + wm + rl) & 2047;
                float best = -1.0e38f; int bi = 0x7fffffff;
#pragma unroll
                for (int fn = 0; fn < 4; ++fn) {
                    const int cg = n0 + wn + fn * 16 + (lane & 15);
                    const float v = acc[fm][fn][r];
                    if (cg != self && v > best) { best = v; bi = cg; }
                }
#pragma unroll
                for (int st = 1; st <= 8; st <<= 1) {   // reduce over the 16-lane col group
                    const float ov = __shfl_xor(best, st);
                    const int   oi = __shfl_xor(bi, st);
                    if (ov > best || (ov == best && oi < bi)) { best = ov; bi = oi; }
                }
                if ((lane & 15) == 0) {                  // lanes 0,16,32,48 -> 4 distinct rows
                    unsigned u = __float_as_uint(best);
                    u = (u & 0x80000000u) ? ~u : (u | 0x80000000u);
                    kv2[wave][rl] = ((unsigned long long)u << 32) | (unsigned)(~bi);
                }
            }
        __syncthreads();
        if (tid < 128) {
            const int wlo = (tid < 64) ? 0 : 2;          // waves covering this row: {0,1} or {2,3}
            const int rl  = tid & 63;
            const unsigned long long a = kv2[wlo][rl], b = kv2[wlo + 1][rl];
            pkey[(size_t)blockIdx.x * 4096 + m0 + tid] = a > b ? a : b;
        }
    }
}

// ---------------------------------------------------------------- BN finalize from 16 per-mblock partials
__global__ __launch_bounds__(256) void bn_final2(const float* __restrict__ ps, const float* __restrict__ ps2,
                                                 float* __restrict__ mu, float* __restrict__ rinv)
{
    const int c = blockIdx.x * 256 + threadIdx.x;  // 0..4095
    const int b = c >> 11, col = c & 2047;
    float s = 0.f, s2 = 0.f;
    for (int i = 0; i < 16; ++i) {
        s  += ps [(size_t)(b * 16 + i) * 2048 + col];
        s2 += ps2[(size_t)(b * 16 + i) * 2048 + col];
    }
    const float m = s * (1.0f / 2048.0f);
    const float v = s2 * (1.0f / 2048.0f) - m * m;   // biased var
    mu[c]   = m;
    rinv[c] = rsqrtf(v + 1e-5f);
}

// ---------------------------------------------------------------- BN apply + ReLU + cast to bf16
__global__ __launch_bounds__(256) void bn_apply(const float* __restrict__ h, const float* __restrict__ mu,
                                                const float* __restrict__ rinv, const float* __restrict__ gamma,
                                                const float* __restrict__ beta, bf16_t* __restrict__ out)
{
    const size_t base = ((size_t)blockIdx.x * 256 + threadIdx.x) * 4;
    const int col = (int)(base & 2047);
    const int br  = (int)(base >> 22);              // row>>11
    f32x4 v = *(const f32x4*)(h + base);
    bf16x4 o;
#pragma unroll
    for (int j = 0; j < 4; ++j) {
        const int c = col + j;
        float t = (v[j] - mu[br * 2048 + c]) * rinv[br * 2048 + c] * gamma[c] + beta[c];
        o[j] = (bf16_t)fmaxf(t, 0.0f);
    }
    *(bf16x4*)(out + base) = o;
}

// ---------------------------------------------------------------- row L2-normalize + cast to bf16
__global__ __launch_bounds__(256) void rownorm(const float* __restrict__ o, bf16_t* __restrict__ feat)
{
    const int row = blockIdx.x;
    const int t = threadIdx.x;
    const float* p = o + (size_t)row * 2048;
    f32x4 v0 = *(const f32x4*)(p + t * 4);
    f32x4 v1 = *(const f32x4*)(p + 1024 + t * 4);
    float ss = v0[0]*v0[0] + v0[1]*v0[1] + v0[2]*v0[2] + v0[3]*v0[3]
             + v1[0]*v1[0] + v1[1]*v1[1] + v1[2]*v1[2] + v1[3]*v1[3];
    __shared__ float S[256];
    S[t] = ss;
    __syncthreads();
    for (int off = 128; off; off >>= 1) { if (t < off) S[t] += S[t + off]; __syncthreads(); }
    const float rn = 1.0f / fmaxf(sqrtf(S[0]), 1e-12f);
    bf16x4 o0, o1;
#pragma unroll
    for (int j = 0; j < 4; ++j) { o0[j] = (bf16_t)(v0[j] * rn); o1[j] = (bf16_t)(v1[j] * rn); }
    *(bf16x4*)(feat + (size_t)row * 2048 + t * 4) = o0;
    *(bf16x4*)(feat + (size_t)row * 2048 + 1024 + t * 4) = o1;
}

// ---------------------------------------------------------------- CC (argmax-combine folded in), 1 block/branch
__global__ __launch_bounds__(1024) void cc_labels(const unsigned long long* __restrict__ pkey,
                                                  int* __restrict__ labg)
{
    __shared__ int A_[2048];
    __shared__ int Bn[2048];
    __shared__ int Y_[2048];
    const int br = blockIdx.x;
    const int t = threadIdx.x;
    // fold: per-row max over the 16 n-block partials -> kNN neighbor
    for (int i = t; i < 2048; i += 1024) {
        const int row = br * 2048 + i;
        unsigned long long k = 0ull;
        for (int nb = 0; nb < 16; ++nb) {
            const unsigned long long v = pkey[(size_t)nb * 4096 + row];
            k = (v > k) ? v : k;
        }
        Y_[i] = (int)~((unsigned)(k & 0xFFFFFFFFull));
        A_[i] = i;
    }
    __syncthreads();
    for (int it = 0; it < 32; ++it) {
        for (int i = t; i < 2048; i += 1024) Bn[i] = min(A_[i], A_[Y_[i]]);   // ln = min(l, l[y])
        __syncthreads();
        for (int i = t; i < 2048; i += 1024) atomicMin(&Bn[Y_[i]], A_[i]);    // ln = ln.at[y].min(l)
        __syncthreads();
        for (int i = t; i < 2048; i += 1024) { int b = Bn[i]; A_[i] = min(b, Bn[b]); } // pointer jump
        __syncthreads();
    }
    for (int i = t; i < 2048; i += 1024) labg[br * 2048 + i] = A_[i];
}

// ---------------------------------------------------------------- per-row contrastive term: lse - possum/poscnt
__global__ __launch_bounds__(256) void loss_rows(const float* __restrict__ sim, const int* __restrict__ labels,
                                                 float* __restrict__ terms)
{
    const int row = blockIdx.x;
    const int br  = row >> 11;
    const int* lab = labels + ((1 - br) << 11);  // mask from the OTHER branch's labels
    const int self = row & 2047;
    const int li = lab[self];
    const int t = threadIdx.x;
    const f32x4* p = (const f32x4*)(sim + (size_t)row * 2048);
    f32x4 a = p[t * 2], b = p[t * 2 + 1];
    float se = 0.f, psum = 0.f; int pc = 0;
#pragma unroll
    for (int j = 0; j < 8; ++j) {
        const int c = t * 8 + j;
        const float v = (j < 4) ? a[j] : b[j - 4];
        if (c == self) continue;
        const float lg = v * 10.0f;   // 1/T
        se += expf(lg);
        if (lab[c] == li) { psum += lg; pc++; }
    }
    __shared__ float SE[256], PS[256]; __shared__ int PC[256];
    SE[t] = se; PS[t] = psum; PC[t] = pc;
    __syncthreads();
    for (int off = 128; off; off >>= 1) {
        if (t < off) { SE[t] += SE[t + off]; PS[t] += PS[t + off]; PC[t] += PC[t + off]; }
        __syncthreads();
    }
    if (t == 0) terms[row] = logf(SE[0]) - PS[0] / (float)PC[0];
}

// ---------------------------------------------------------------- final deterministic reduce
__global__ __launch_bounds__(1024) void final_reduce(const float* __restrict__ terms, float* __restrict__ out)
{
    const int t = threadIdx.x;
    float s = terms[t] + terms[t + 1024] + terms[t + 2048] + terms[t + 3072];
    __shared__ float S[1024];
    S[t] = s;
    __syncthreads();
    for (int off = 512; off; off >>= 1) { if (t < off) S[t] += S[t + off]; __syncthreads(); }
    if (t == 0) out[0] = S[0] * (1.0f / 4096.0f);   // (L1+L2)/2, each mean over 2048 rows
}

// ---------------------------------------------------------------- launch
extern "C" void kernel_launch(void* const* d_in, const int* in_sizes, int n_in,
                              void* d_out, int out_size, void* d_ws, size_t ws_size,
                              hipStream_t stream)
{
    const float* x1    = (const float*)d_in[0];
    const float* x2    = (const float*)d_in[1];
    const float* W1    = (const float*)d_in[2];
    const float* b1    = (const float*)d_in[3];
    const float* gamma = (const float*)d_in[4];
    const float* beta  = (const float*)d_in[5];
    const float* W2    = (const float*)d_in[6];
    const float* b2    = (const float*)d_in[7];

    char* ws = (char*)d_ws;
    const size_t MB = 1024ull * 1024ull;
    const size_t NN = 2048ull * 2048ull;
    // Region plan (reuse as regions go dead):
    //  [0,8M)   W1b      (dead after GEMM1)
    //  [8,16M)  W2b      (dead after GEMM2)
    //  [16,32M) xcatb -> hnb (xcatb dead after GEMM1; hnb dead after GEMM2)
    //  [32,64M) h -> o   (dead after rownorm)
    //  [0,32M)  sim      (written by GEMM3 after W1b/W2b/hnb dead)
    //  [64,80M) featb
    //  [80M..)  partials + small buffers
    bf16_t* W1b    = (bf16_t*)(ws + 0);
    bf16_t* W2b    = (bf16_t*)(ws + 8 * MB);
    bf16_t* xcatb  = (bf16_t*)(ws + 16 * MB);
    bf16_t* hnb    = (bf16_t*)(ws + 16 * MB);
    float*  hbuf   = (float*)(ws + 32 * MB);
    float*  sim    = (float*)(ws + 0);
    bf16_t* featb  = (bf16_t*)(ws + 64 * MB);
    float*  psA    = (float*)(ws + 80 * MB);              // [32][2048] col sums
    float*  psB    = psA + 32 * 2048;                      // [32][2048] col sumsq
    float*  mu     = psB + 32 * 2048;                      // [2][2048]
    float*  rinv   = mu + 4096;
    unsigned long long* pkey = (unsigned long long*)(rinv + 4096);  // [16][4096]
    int*    labels = (int*)(pkey + 16 * 4096);
    float*  terms  = (float*)(labels + 4096);

    // fused casts
    cast_all<<<16384, 256, 0, stream>>>(x1, x2, W1, W2, xcatb, W1b, W2b);

    // h = xcat @ W1^T + b1 (M=4096,N=2048,K=2048), fused BN-stat partials
    gemm_bt<<<dim3(16, 32), 256, 0, stream>>>(xcatb, W1b, b1, hbuf, 2048, 2048, 1 << 30, 0,
                                              1, psA, psB, nullptr);
    bn_final2<<<16, 256, 0, stream>>>(psA, psB, mu, rinv);
    bn_apply<<<8192, 256, 0, stream>>>(hbuf, mu, rinv, gamma, beta, hnb);

    // o = hn @ W2^T + b2
    gemm_bt<<<dim3(16, 32), 256, 0, stream>>>(hnb, W2b, b2, hbuf, 2048, 2048, 1 << 30, 0,
                                              0, nullptr, nullptr, nullptr);

    // feat = normalize(o) -> bf16
    rownorm<<<4096, 256, 0, stream>>>(hbuf, featb);

    // sim = [feat1@feat1^T ; feat2@feat2^T], fused row-argmax partials
    gemm_bt<<<dim3(16, 32), 256, 0, stream>>>(featb, featb, nullptr, sim, 2048, 2048, 2048, (long long)NN,
                                              2, nullptr, nullptr, pkey);

    // CC (argmax folded) -> loss
    cc_labels<<<2, 1024, 0, stream>>>(pkey, labels);
    loss_rows<<<4096, 256, 0, stream>>>(sim, labels, terms);
    final_reduce<<<1, 1024, 0, stream>>>(terms, (float*)d_out);
}

// Round 6
// 231.405 us; speedup vs baseline: 1.3549x; 1.0570x over previous
//
#include <hip/hip_runtime.h>
#include <hip/hip_bf16.h>

typedef __bf16 bf16_t;
typedef __bf16 bf16x4 __attribute__((ext_vector_type(4)));
typedef __bf16 bf16x8 __attribute__((ext_vector_type(8)));
typedef float  f32x4  __attribute__((ext_vector_type(4)));

// ---------------------------------------------------------------- helpers
__device__ __forceinline__ void gload_lds16(const void* g, void* l)
{
    __builtin_amdgcn_global_load_lds((__attribute__((address_space(1))) void*)g,
                                     (__attribute__((address_space(3))) void*)l,
                                     16, 0, 0);
}

// ---------------------------------------------------------------- fused fp32 -> bf16 casts (x1|x2 -> xcat, W1, W2)
__global__ __launch_bounds__(256) void cast_all(const float* __restrict__ x1, const float* __restrict__ x2,
                                                const float* __restrict__ W1, const float* __restrict__ W2,
                                                bf16_t* __restrict__ xcatb, bf16_t* __restrict__ W1b,
                                                bf16_t* __restrict__ W2b)
{
    const size_t i  = ((size_t)blockIdx.x * 256 + threadIdx.x) * 4;
    const size_t M4 = 1ull << 22;              // 4M elements per region
    const size_t r  = i >> 22;
    const size_t off = i & (M4 - 1);
    const float* src; bf16_t* dst;
    if (r == 0)      { src = x1; dst = xcatb; }
    else if (r == 1) { src = x2; dst = xcatb + M4; }
    else if (r == 2) { src = W1; dst = W1b; }
    else             { src = W2; dst = W2b; }
    f32x4 v = *(const f32x4*)(src + off);
    bf16x4 o;
    o[0] = (bf16_t)v[0]; o[1] = (bf16_t)v[1]; o[2] = (bf16_t)v[2]; o[3] = (bf16_t)v[3];
    *(bf16x4*)(dst + off) = o;
}

// ---------------------------------------------------------------- NT GEMM, R1/m97 structure: 128x128 tile, BK=64
// C[m,n] = sum_k A[m,k]*B[n,k] + bias[n]; 4 waves (2x2), each wave 64x64 via 4x4 frags of 16x16x32 MFMA.
// mode 1: + per-mblock column sum/sumsq partials (BN stats), from exact fp32 acc.
// mode 2: + rn_m*rn_n scaling of acc (row-normalization folded in), then per-nblock row argmax partials.
// mode 3: + per-nblock row sum-of-squares partials (for L2 row norms), from exact fp32 acc.
// c_bf16: write C as bf16 (else fp32).
__global__ __launch_bounds__(256) void gemm_bt(
    const bf16_t* __restrict__ A, const bf16_t* __restrict__ B,
    const float* __restrict__ bias, void* __restrict__ Cv,
    int N, int K, int rows_per_batch, long long b_batch_stride,
    int mode, int c_bf16,
    float* __restrict__ ps, float* __restrict__ ps2,
    float* __restrict__ rsq, const float* __restrict__ rnv,
    unsigned long long* __restrict__ pkey)
{
    __shared__ bf16_t lsA[128 * 64];
    __shared__ bf16_t lsB[128 * 64];
    __shared__ float  cs2[4][64];                 // mode1: per-wave col sums   (unique writer)
    __shared__ float  cq2[4][64];                 // mode1: per-wave col sumsqs (unique writer)
    __shared__ float  rq2[4][64];                 // mode3: per-wave row sumsqs (unique writer)
    __shared__ unsigned long long kv2[4][64];     // mode2: per-wave row keys   (unique writer)
    const int tid  = threadIdx.x;
    const int lane = tid & 63;
    const int wave = tid >> 6;
    const int wm   = (wave >> 1) * 64;
    const int wn   = (wave & 1) * 64;
    const int m0   = blockIdx.y * 128;
    const int n0   = blockIdx.x * 128;
    const bf16_t* Bb = B + (long long)(m0 / rows_per_batch) * b_batch_stride;

    f32x4 acc[4][4] = {};

    const int srow = tid >> 3;        // staging: 256 threads cover 32 rows x 8 chunks of 16B
    const int scol = (tid & 7) * 8;   // element offset within BK
    for (int kt = 0; kt < K; kt += 64) {
#pragma unroll
        for (int i = 0; i < 4; ++i) {
            const int r = i * 32 + srow;
            // LDS dest = wave-uniform base + lane*16 (linear, required for global_load_lds)
            gload_lds16(A  + (size_t)(m0 + r) * K + kt + scol, lsA + r * 64 + scol);
            gload_lds16(Bb + (size_t)(n0 + r) * K + kt + scol, lsB + r * 64 + scol);
        }
        __syncthreads();  // compiler drains vmcnt before barrier
#pragma unroll
        for (int ks = 0; ks < 2; ++ks) {
            const int kk = ks * 32 + (lane >> 4) * 8;
            bf16x8 af[4], bfr[4];
#pragma unroll
            for (int f = 0; f < 4; ++f) {
                af[f]  = *(const bf16x8*)&lsA[(wm + f * 16 + (lane & 15)) * 64 + kk];
                bfr[f] = *(const bf16x8*)&lsB[(wn + f * 16 + (lane & 15)) * 64 + kk];
            }
#pragma unroll
            for (int fm = 0; fm < 4; ++fm)
#pragma unroll
                for (int fn = 0; fn < 4; ++fn)
                    acc[fm][fn] = __builtin_amdgcn_mfma_f32_16x16x32_bf16(af[fm], bfr[fn], acc[fm][fn], 0, 0, 0);
        }
        __syncthreads();
    }

    // ---- mode2: fold row-normalization in: acc[m][n] *= rn[m]*rn[n]
    if (mode == 2) {
        const int rnb = (m0 >> 11) * 2048;   // branch base for B-side rn
#pragma unroll
        for (int fm = 0; fm < 4; ++fm) {
            const int mb = m0 + wm + fm * 16 + ((lane >> 4) << 2);
            const f32x4 rm = *(const f32x4*)&rnv[mb];
#pragma unroll
            for (int fn = 0; fn < 4; ++fn) {
                const float rc = rnv[rnb + n0 + wn + fn * 16 + (lane & 15)];
#pragma unroll
                for (int r = 0; r < 4; ++r)
                    acc[fm][fn][r] *= rm[r] * rc;
            }
        }
    }

    // ---- C write (+bias). C/D layout: col = lane&15, row = (lane>>4)*4 + reg  [m89-verified]
#pragma unroll
    for (int fm = 0; fm < 4; ++fm) {
        const int rb = m0 + wm + fm * 16 + ((lane >> 4) << 2);
#pragma unroll
        for (int fn = 0; fn < 4; ++fn) {
            const int colg = n0 + wn + fn * 16 + (lane & 15);
            const float bv = bias ? bias[colg] : 0.0f;
            if (c_bf16) {
                bf16_t* Cb = (bf16_t*)Cv;
#pragma unroll
                for (int r = 0; r < 4; ++r)
                    Cb[(size_t)(rb + r) * N + colg] = (bf16_t)(acc[fm][fn][r] + bv);
            } else {
                float* Cf = (float*)Cv;
#pragma unroll
                for (int r = 0; r < 4; ++r)
                    Cf[(size_t)(rb + r) * N + colg] = acc[fm][fn][r] + bv;
            }
        }
    }

    if (mode == 1) {
        // column sum/sumsq over this block's 128 rows. Waves {0,2} share cols 0..63, {1,3} cols 64..127.
#pragma unroll
        for (int fn = 0; fn < 4; ++fn) {
            const int cl = fn * 16 + (lane & 15);      // 0..63 within wave's col range
            const float bv = bias[n0 + wn + cl];
            float s = 0.f, q = 0.f;
#pragma unroll
            for (int fm = 0; fm < 4; ++fm)
#pragma unroll
                for (int r = 0; r < 4; ++r) {
                    const float v = acc[fm][fn][r] + bv;
                    s += v; q += v * v;
                }
            s += __shfl_xor(s, 16); q += __shfl_xor(q, 16);
            s += __shfl_xor(s, 32); q += __shfl_xor(q, 32);
            if (lane < 16) { cs2[wave][cl] = s; cq2[wave][cl] = q; }
        }
        __syncthreads();
        if (tid < 128) {
            const int wlo = (tid < 64) ? 0 : 1;
            const int cl  = tid & 63;
            ps [(size_t)blockIdx.y * 2048 + n0 + tid] = cs2[wlo][cl] + cs2[wlo + 2][cl];
            ps2[(size_t)blockIdx.y * 2048 + n0 + tid] = cq2[wlo][cl] + cq2[wlo + 2][cl];
        }
    } else if (mode == 3) {
        // row sum-of-squares of (acc+bias) over this block's 128 cols. Waves {0,1} share rows 0..63, {2,3} rows 64..127.
#pragma unroll
        for (int fm = 0; fm < 4; ++fm)
#pragma unroll
            for (int r = 0; r < 4; ++r) {
                float q = 0.f;
#pragma unroll
                for (int fn = 0; fn < 4; ++fn) {
                    const float v = acc[fm][fn][r] + bias[n0 + wn + fn * 16 + (lane & 15)];
                    q += v * v;
                }
                q += __shfl_xor(q, 1); q += __shfl_xor(q, 2);
                q += __shfl_xor(q, 4); q += __shfl_xor(q, 8);
                if ((lane & 15) == 0)
                    rq2[wave][fm * 16 + ((lane >> 4) << 2) + r] = q;
            }
        __syncthreads();
        if (tid < 128) {
            const int wlo = (tid < 64) ? 0 : 2;
            const int rl  = tid & 63;
            rsq[(size_t)blockIdx.x * 4096 + m0 + tid] = rq2[wlo][rl] + rq2[wlo + 1][rl];
        }
    } else if (mode == 2) {
        // row argmax over this block's 128 cols (scaled acc); key = ordered(val)<<32 | ~col.
#pragma unroll
        for (int fm = 0; fm < 4; ++fm)
#pragma unroll
            for (int r = 0; r < 4; ++r) {
                const int rl   = fm * 16 + ((lane >> 4) << 2) + r;
                const int self = (m0 + wm + rl) & 2047;
                float best = -1.0e38f; int bi = 0x7fffffff;
#pragma unroll
                for (int fn = 0; fn < 4; ++fn) {
                    const int cg = n0 + wn + fn * 16 + (lane & 15);
                    const float v = acc[fm][fn][r];
                    if (cg != self && v > best) { best = v; bi = cg; }
                }
#pragma unroll
                for (int st = 1; st <= 8; st <<= 1) {
                    const float ov = __shfl_xor(best, st);
                    const int   oi = __shfl_xor(bi, st);
                    if (ov > best || (ov == best && oi < bi)) { best = ov; bi = oi; }
                }
                if ((lane & 15) == 0) {
                    unsigned u = __float_as_uint(best);
                    u = (u & 0x80000000u) ? ~u : (u | 0x80000000u);
                    kv2[wave][rl] = ((unsigned long long)u << 32) | (unsigned)(~bi);
                }
            }
        __syncthreads();
        if (tid < 128) {
            const int wlo = (tid < 64) ? 0 : 2;
            const int rl  = tid & 63;
            const unsigned long long a = kv2[wlo][rl], b = kv2[wlo + 1][rl];
            pkey[(size_t)blockIdx.x * 4096 + m0 + tid] = a > b ? a : b;
        }
    }
}

// ---------------------------------------------------------------- BN finalize from 16 per-mblock partials
__global__ __launch_bounds__(256) void bn_final2(const float* __restrict__ ps, const float* __restrict__ ps2,
                                                 float* __restrict__ mu, float* __restrict__ rinv)
{
    const int c = blockIdx.x * 256 + threadIdx.x;  // 0..4095
    const int b = c >> 11, col = c & 2047;
    float s = 0.f, s2 = 0.f;
    for (int i = 0; i < 16; ++i) {
        s  += ps [(size_t)(b * 16 + i) * 2048 + col];
        s2 += ps2[(size_t)(b * 16 + i) * 2048 + col];
    }
    const float m = s * (1.0f / 2048.0f);
    const float v = s2 * (1.0f / 2048.0f) - m * m;   // biased var
    mu[c]   = m;
    rinv[c] = rsqrtf(v + 1e-5f);
}

// ---------------------------------------------------------------- BN apply + ReLU on bf16 h -> bf16 hn
__global__ __launch_bounds__(256) void bn_apply(const bf16_t* __restrict__ h, const float* __restrict__ mu,
                                                const float* __restrict__ rinv, const float* __restrict__ gamma,
                                                const float* __restrict__ beta, bf16_t* __restrict__ out)
{
    const size_t base = ((size_t)blockIdx.x * 256 + threadIdx.x) * 8;
    const int col = (int)(base & 2047);
    const int br  = (int)(base >> 22);              // (row>>11)
    bf16x8 v = *(const bf16x8*)(h + base);
    bf16x8 o;
#pragma unroll
    for (int j = 0; j < 8; ++j) {
        const int c = col + j;
        const float f = (float)v[j];
        const float t = (f - mu[br * 2048 + c]) * rinv[br * 2048 + c] * gamma[c] + beta[c];
        o[j] = (bf16_t)fmaxf(t, 0.0f);
    }
    *(bf16x8*)(out + base) = o;
}

// ---------------------------------------------------------------- rn[r] = 1/max(||o_r||, 1e-12) from 16 partials
__global__ __launch_bounds__(256) void norm_final(const float* __restrict__ rsq, float* __restrict__ rn)
{
    const int r = blockIdx.x * 256 + threadIdx.x;   // 0..4095
    float s = 0.f;
    for (int nb = 0; nb < 16; ++nb) s += rsq[(size_t)nb * 4096 + r];
    rn[r] = 1.0f / fmaxf(sqrtf(s), 1e-12f);
}

// ---------------------------------------------------------------- CC (argmax-combine folded), early-exit, 1 block/branch
__global__ __launch_bounds__(1024) void cc_labels(const unsigned long long* __restrict__ pkey,
                                                  int* __restrict__ labg)
{
    __shared__ int A_[2048];
    __shared__ int Bn[2048];
    __shared__ int Y_[2048];
    __shared__ int chg;
    const int br = blockIdx.x;
    const int t = threadIdx.x;
    if (t == 0) chg = 0;
    // fold: per-row max over the 16 n-block partials -> kNN neighbor
    for (int i = t; i < 2048; i += 1024) {
        const int row = br * 2048 + i;
        unsigned long long k = 0ull;
        for (int nb = 0; nb < 16; ++nb) {
            const unsigned long long v = pkey[(size_t)nb * 4096 + row];
            k = (v > k) ? v : k;
        }
        Y_[i] = (int)~((unsigned)(k & 0xFFFFFFFFull));
        A_[i] = i;
    }
    __syncthreads();
    // deterministic monotone map: early exit at fixpoint == exact 32-iter result
    for (int it = 0; it < 32; ++it) {
        for (int i = t; i < 2048; i += 1024) Bn[i] = min(A_[i], A_[Y_[i]]);   // ln = min(l, l[y])
        __syncthreads();
        for (int i = t; i < 2048; i += 1024) atomicMin(&Bn[Y_[i]], A_[i]);    // ln = ln.at[y].min(l)
        __syncthreads();
        int ch = 0;
        for (int i = t; i < 2048; i += 1024) {
            const int b = Bn[i];
            const int nv = min(b, Bn[b]);                                      // pointer jump
            if (nv != A_[i]) { ch = 1; A_[i] = nv; }
        }
        if (ch) atomicOr(&chg, 1);
        __syncthreads();
        const int c = chg;
        __syncthreads();
        if (t == 0) chg = 0;
        if (!c) break;
    }
    for (int i = t; i < 2048; i += 1024) labg[br * 2048 + i] = A_[i];
}

// ---------------------------------------------------------------- per-row contrastive term: lse - possum/poscnt
__global__ __launch_bounds__(256) void loss_rows(const float* __restrict__ sim, const int* __restrict__ labels,
                                                 float* __restrict__ terms)
{
    const int row = blockIdx.x;
    const int br  = row >> 11;
    const int* lab = labels + ((1 - br) << 11);  // mask from the OTHER branch's labels
    const int self = row & 2047;
    const int li = lab[self];
    const int t = threadIdx.x;
    const f32x4* p = (const f32x4*)(sim + (size_t)row * 2048);
    f32x4 a = p[t * 2], b = p[t * 2 + 1];
    float se = 0.f, psum = 0.f; int pc = 0;
#pragma unroll
    for (int j = 0; j < 8; ++j) {
        const int c = t * 8 + j;
        const float v = (j < 4) ? a[j] : b[j - 4];
        if (c == self) continue;
        const float lg = v * 10.0f;   // 1/T
        se += expf(lg);
        if (lab[c] == li) { psum += lg; pc++; }
    }
    __shared__ float SE[256], PS[256]; __shared__ int PC[256];
    SE[t] = se; PS[t] = psum; PC[t] = pc;
    __syncthreads();
    for (int off = 128; off; off >>= 1) {
        if (t < off) { SE[t] += SE[t + off]; PS[t] += PS[t + off]; PC[t] += PC[t + off]; }
        __syncthreads();
    }
    if (t == 0) terms[row] = logf(SE[0]) - PS[0] / (float)PC[0];
}

// ---------------------------------------------------------------- final deterministic reduce
__global__ __launch_bounds__(1024) void final_reduce(const float* __restrict__ terms, float* __restrict__ out)
{
    const int t = threadIdx.x;
    float s = terms[t] + terms[t + 1024] + terms[t + 2048] + terms[t + 3072];
    __shared__ float S[1024];
    S[t] = s;
    __syncthreads();
    for (int off = 512; off; off >>= 1) { if (t < off) S[t] += S[t + off]; __syncthreads(); }
    if (t == 0) out[0] = S[0] * (1.0f / 4096.0f);   // (L1+L2)/2, each mean over 2048 rows
}

// ---------------------------------------------------------------- launch
extern "C" void kernel_launch(void* const* d_in, const int* in_sizes, int n_in,
                              void* d_out, int out_size, void* d_ws, size_t ws_size,
                              hipStream_t stream)
{
    const float* x1    = (const float*)d_in[0];
    const float* x2    = (const float*)d_in[1];
    const float* W1    = (const float*)d_in[2];
    const float* b1    = (const float*)d_in[3];
    const float* gamma = (const float*)d_in[4];
    const float* beta  = (const float*)d_in[5];
    const float* W2    = (const float*)d_in[6];
    const float* b2    = (const float*)d_in[7];

    char* ws = (char*)d_ws;
    const size_t MB = 1024ull * 1024ull;
    const size_t NN = 2048ull * 2048ull;
    // Region plan (reuse as regions go dead):
    //  [0,8M)   W1b      (dead after GEMM1)
    //  [8,16M)  W2b      (dead after GEMM2)
    //  [16,32M) xcatb -> hnb (xcatb dead after GEMM1; hnb dead after GEMM2)
    //  [32,48M) h_bf16   (GEMM1 C; dead after bn_apply)
    //  [64,80M) o_bf16   (GEMM2 C; read by GEMM3)
    //  [0,32M)  sim fp32 (GEMM3 C; W1b/W2b dead by then)
    //  [80M..)  partials + small buffers
    bf16_t* W1b    = (bf16_t*)(ws + 0);
    bf16_t* W2b    = (bf16_t*)(ws + 8 * MB);
    bf16_t* xcatb  = (bf16_t*)(ws + 16 * MB);
    bf16_t* hnb    = (bf16_t*)(ws + 16 * MB);
    bf16_t* hb16   = (bf16_t*)(ws + 32 * MB);
    bf16_t* ob16   = (bf16_t*)(ws + 64 * MB);
    float*  sim    = (float*)(ws + 0);
    float*  psA    = (float*)(ws + 80 * MB);               // [32][2048] col sums
    float*  psB    = psA + 32 * 2048;                       // [32][2048] col sumsq
    float*  rsq    = psB + 32 * 2048;                       // [16][4096] row sumsq
    float*  mu     = rsq + 16 * 4096;                       // [2][2048]
    float*  rinv   = mu + 4096;
    float*  rn     = rinv + 4096;                           // [4096]
    unsigned long long* pkey = (unsigned long long*)(rn + 4096);  // [16][4096]
    int*    labels = (int*)(pkey + 16 * 4096);
    float*  terms  = (float*)(labels + 4096);

    // fused casts
    cast_all<<<16384, 256, 0, stream>>>(x1, x2, W1, W2, xcatb, W1b, W2b);

    // h = xcat @ W1^T + b1 (M=4096,N=2048,K=2048) -> bf16, fused BN-stat partials (exact fp32 acc)
    gemm_bt<<<dim3(16, 32), 256, 0, stream>>>(xcatb, W1b, b1, hb16, 2048, 2048, 1 << 30, 0,
                                              1, 1, psA, psB, nullptr, nullptr, nullptr);
    bn_final2<<<16, 256, 0, stream>>>(psA, psB, mu, rinv);
    bn_apply<<<4096, 256, 0, stream>>>(hb16, mu, rinv, gamma, beta, hnb);

    // o = hn @ W2^T + b2 -> bf16, fused row-sumsq partials (exact fp32 acc)
    gemm_bt<<<dim3(16, 32), 256, 0, stream>>>(hnb, W2b, b2, ob16, 2048, 2048, 1 << 30, 0,
                                              3, 1, nullptr, nullptr, rsq, nullptr, nullptr);
    norm_final<<<16, 256, 0, stream>>>(rsq, rn);

    // sim = [o1@o1^T ; o2@o2^T] * rn_m*rn_n  (normalization folded), fused row-argmax partials
    gemm_bt<<<dim3(16, 32), 256, 0, stream>>>(ob16, ob16, nullptr, sim, 2048, 2048, 2048, (long long)NN,
                                              2, 0, nullptr, nullptr, nullptr, rn, pkey);

    // CC (argmax folded, early-exit) -> loss
    cc_labels<<<2, 1024, 0, stream>>>(pkey, labels);
    loss_rows<<<4096, 256, 0, stream>>>(sim, labels, terms);
    final_reduce<<<1, 1024, 0, stream>>>(terms, (float*)d_out);
}